// Round 6
// baseline (383.208 us; speedup 1.0000x reference)
//
#include <hip/hip_runtime.h>
#include <hip/hip_bf16.h>

#define FIN 4096
#define FOUT 4096
#define HEADS 4
#define ROWS_PER_HEAD (FOUT / HEADS)  // 1024
#define M_DIM 4096                    // 2*2048 flattened batch*seq

typedef __attribute__((ext_vector_type(8))) short bf16x8;   // 8 bf16 = 4 VGPRs
typedef __attribute__((ext_vector_type(4))) float floatx4;  // MFMA accum

// ---------------------------------------------------------------------------
// Kernel 1: W_i = conv3x3_per_head(W) + bias + sigmoid(sk)*W    (fp32 -> bf16)
// 8 outputs/thread along fin; float4 row loads + 2 edge scalars; 16B store.
// (Activation cast is now fused into the GEMM's A-staging — R6.)
// ---------------------------------------------------------------------------
__global__ __launch_bounds__(256) void transform_w(
    const float* __restrict__ W,
    const float* __restrict__ cw,   // [HEADS][3][3]
    const float* __restrict__ cb,   // [HEADS]
    const float* __restrict__ sk,   // [HEADS]
    __hip_bfloat16* __restrict__ Wt) {
  int gid = blockIdx.x * 256 + threadIdx.x;  // 0 .. FOUT*(FIN/8)-1
  int o = gid >> 9;                          // output row (FIN/8 = 512)
  int fs = (gid & 511) << 3;                 // fin start, multiple of 8
  int h = o >> 10;                           // head
  int r = o & (ROWS_PER_HEAD - 1);

  float kk[3][3];
#pragma unroll
  for (int i = 0; i < 3; i++)
#pragma unroll
    for (int j = 0; j < 3; j++) kk[i][j] = cw[h * 9 + i * 3 + j];
  float sig = 1.0f / (1.0f + __expf(-sk[h]));

  float acc[8];
#pragma unroll
  for (int j = 0; j < 8; j++) acc[j] = cb[h];

#pragma unroll
  for (int dr = -1; dr <= 1; dr++) {
    int rr = r + dr;
    if (rr < 0 || rr >= ROWS_PER_HEAD) continue;
    const float* rp = W + ((size_t)(h * ROWS_PER_HEAD + rr)) * FIN + fs;
    float a[10];
    float4 v0 = *(const float4*)rp;
    float4 v1 = *(const float4*)(rp + 4);
    a[1] = v0.x; a[2] = v0.y; a[3] = v0.z; a[4] = v0.w;
    a[5] = v1.x; a[6] = v1.y; a[7] = v1.z; a[8] = v1.w;
    a[0] = (fs > 0) ? rp[-1] : 0.0f;
    a[9] = (fs + 8 < FIN) ? rp[8] : 0.0f;
#pragma unroll
    for (int j = 0; j < 8; j++)
      acc[j] += kk[dr + 1][0] * a[j] + kk[dr + 1][1] * a[j + 1] +
                kk[dr + 1][2] * a[j + 2];
    if (dr == 0) {
#pragma unroll
      for (int j = 0; j < 8; j++) acc[j] += sig * a[j + 1];
    }
  }
  __hip_bfloat16 t[8];
#pragma unroll
  for (int j = 0; j < 8; j++) t[j] = __float2bfloat16(acc[j]);
  *(bf16x8*)(&Wt[(size_t)o * FIN + fs]) = *(bf16x8*)t;
}

// ---------------------------------------------------------------------------
// Kernel 2: C[m][n] = sum_k A[m][k] * B[n][k]
// A: fp32 (raw activations, cast fused into fragment read). B: bf16 (Wt).
// m97-structure, 128x128 tile, BK=32, 4 waves, 4x4 mfma_f32_16x16x32_bf16.
//
// A LDS layout (fp32, rows of 128B = 8 x 16B chunks): slot s of row r holds
// global chunk g = s ^ (r&7). Fragment lane (fr,quad) reads slots
// (2q)^(fr&7), (2q+1)^(fr&7): each 32-lane phase covers all 8 bank-groups
// 4-way = natural b128 aliasing, zero extra conflicts.
// B LDS layout: R4-verified XOR chunk swizzle (conflicts measured 0).
// ---------------------------------------------------------------------------
__device__ static inline void gload_lds16(const void* g, void* l) {
  __builtin_amdgcn_global_load_lds(
      (const __attribute__((address_space(1))) void*)g,
      (__attribute__((address_space(3))) void*)l, 16, 0, 0);
}

__global__ __launch_bounds__(256, 3) void gemm_nt(
    const float* __restrict__ A,           // [M][K] fp32
    const __hip_bfloat16* __restrict__ B,  // [N][K] bf16 (= W_i)
    float* __restrict__ C,                 // [M][N] fp32
    int M, int N, int K) {
  __shared__ float As[128 * 32];           // 16 KB
  __shared__ __hip_bfloat16 Bs[128 * 32];  // 8 KB

  const int tid = threadIdx.x;
  const int lane = tid & 63;
  const int wave = tid >> 6;  // 0..3
  const int tile_m = blockIdx.y * 128;
  const int tile_n = blockIdx.x * 128;

  const int fr = lane & 15;    // fragment row (m for A, n for B^T)
  const int quad = lane >> 4;  // k-chunk selector (k = quad*8 + j)
  const int wm = (wave & 1) * 64;
  const int wn = (wave >> 1) * 64;

  // B swizzle (bf16 rows of 64B = 4 chunks): koff = (quad ^ ((fr>>1)&3))*8
  const int koffB = (quad ^ ((fr >> 1) & 3)) * 8;
  // A swizzle (fp32 rows of 128B = 8 chunks)
  const int selA = fr & 7;
  const int sA0 = (2 * quad) ^ selA;      // slot of k = quad*8 .. +3
  const int sA1 = (2 * quad + 1) ^ selA;  // slot of k = quad*8+4 .. +7

  floatx4 acc[4][4];
#pragma unroll
  for (int i = 0; i < 4; i++)
#pragma unroll
    for (int j = 0; j < 4; j++) acc[i][j] = (floatx4){0.f, 0.f, 0.f, 0.f};

  for (int k0 = 0; k0 < K; k0 += 32) {
    // A: 128x32 fp32 = 1024 chunks of 16B (4 fp32); 4 per thread.
#pragma unroll
    for (int t = 0; t < 4; t++) {
      int base = (t * 4 + wave) * 64;  // wave-uniform chunk base
      int p = base + lane;             // LDS chunk position
      int row = p >> 3;
      int g = (p & 7) ^ (row & 7);     // permuted global chunk
      gload_lds16(&A[(size_t)(tile_m + row) * K + k0 + g * 4],
                  &As[base * 4]);
    }
    // B: 128x32 bf16 = 512 chunks of 16B; 2 per thread.
#pragma unroll
    for (int t = 0; t < 2; t++) {
      int base = (t * 4 + wave) * 64;
      int p = base + lane;
      int row = p >> 2;
      int kq = ((p & 3) ^ ((row >> 1) & 3)) * 8;
      gload_lds16(&B[(size_t)(tile_n + row) * K + k0 + kq],
                  &Bs[base * 8]);
    }
    __syncthreads();

    bf16x8 a_frag[4], b_frag[4];
#pragma unroll
    for (int i = 0; i < 4; i++) {
      const float* ap = &As[(wm + i * 16 + fr) * 32];
      floatx4 lo = *(const floatx4*)(ap + sA0 * 4);
      floatx4 hi = *(const floatx4*)(ap + sA1 * 4);
      __hip_bfloat16 t8[8];
#pragma unroll
      for (int j = 0; j < 4; j++) {
        t8[j] = __float2bfloat16(lo[j]);
        t8[4 + j] = __float2bfloat16(hi[j]);
      }
      a_frag[i] = *(bf16x8*)t8;
      b_frag[i] = *(const bf16x8*)(&Bs[(wn + i * 16 + fr) * 32 + koffB]);
    }
#pragma unroll
    for (int i = 0; i < 4; i++)
#pragma unroll
      for (int j = 0; j < 4; j++)
        acc[i][j] = __builtin_amdgcn_mfma_f32_16x16x32_bf16(
            a_frag[i], b_frag[j], acc[i][j], 0, 0, 0);
    __syncthreads();
  }

  // Epilogue: C/D layout col = lane&15, row = quad*4 + reg. FP32 stores.
#pragma unroll
  for (int i = 0; i < 4; i++) {
    int m_base = tile_m + wm + i * 16 + quad * 4;
#pragma unroll
    for (int j = 0; j < 4; j++) {
      int n = tile_n + wn + j * 16 + fr;
#pragma unroll
      for (int r = 0; r < 4; r++) {
        C[(size_t)(m_base + r) * N + n] = acc[i][j][r];
      }
    }
  }
}

// ---------------------------------------------------------------------------
extern "C" void kernel_launch(void* const* d_in, const int* in_sizes, int n_in,
                              void* d_out, int out_size, void* d_ws,
                              size_t ws_size, hipStream_t stream) {
  const float* inp = (const float*)d_in[0];     // [2,2048,4096] fp32
  const float* W = (const float*)d_in[1];       // [4096,4096] fp32
  const float* conv_w = (const float*)d_in[2];  // [4,1,3,3] fp32
  const float* conv_b = (const float*)d_in[3];  // [4] fp32
  const float* sk_wt = (const float*)d_in[4];   // [4,1,1] fp32
  float* out = (float*)d_out;                   // [2,2048,4096] fp32

  __hip_bfloat16* Wt = (__hip_bfloat16*)d_ws;   // 32 MB

  // 1) transformed weight (bf16) into workspace
  transform_w<<<(FOUT * FIN / 8) / 256, 256, 0, stream>>>(W, conv_w, conv_b,
                                                          sk_wt, Wt);
  // 2) out[m][n] = sum_k inp[m][k] * Wt[n][k]  (A cast fused in staging)
  dim3 grid(FOUT / 128, M_DIM / 128);
  gemm_nt<<<grid, 256, 0, stream>>>(inp, Wt, out, M_DIM, FOUT, FIN);
}

// Round 7
// 297.630 us; speedup vs baseline: 1.2875x; 1.2875x over previous
//
#include <hip/hip_runtime.h>
#include <hip/hip_bf16.h>

#define FIN 4096
#define FOUT 4096
#define HEADS 4
#define ROWS_PER_HEAD (FOUT / HEADS)  // 1024
#define M_DIM 4096                    // 2*2048 flattened batch*seq

typedef __attribute__((ext_vector_type(8))) short bf16x8;   // 8 bf16 = 4 VGPRs
typedef __attribute__((ext_vector_type(4))) float floatx4;  // MFMA accum

#define CAST_BLOCKS ((M_DIM * FIN) / (256 * 8))      // 8192
#define TRANS_BLOCKS ((FOUT * FIN / 8) / 256)        // 8192

// ---------------------------------------------------------------------------
// Kernel 1 (merged prep, R5-verified): blocks [0, CAST_BLOCKS) cast inp
// fp32->bf16; blocks [CAST_BLOCKS, +TRANS_BLOCKS) compute W_i = conv3x3 +
// bias + sigmoid(sk)*W (fp32 in, bf16 out). 8 elem/thread, coalesced.
// ---------------------------------------------------------------------------
__global__ __launch_bounds__(256) void prep(
    const float* __restrict__ x,    // activations [M_DIM][FIN]
    __hip_bfloat16* __restrict__ y, // bf16 activations out
    const float* __restrict__ W,
    const float* __restrict__ cw,   // [HEADS][3][3]
    const float* __restrict__ cb,   // [HEADS]
    const float* __restrict__ sk,   // [HEADS]
    __hip_bfloat16* __restrict__ Wt) {
  if (blockIdx.x < CAST_BLOCKS) {
    int idx = blockIdx.x * 256 + threadIdx.x;  // one per 8 elements
    const float4* xv = (const float4*)x;
    float4 a = xv[idx * 2];
    float4 b = xv[idx * 2 + 1];
    __hip_bfloat16 t[8];
    t[0] = __float2bfloat16(a.x); t[1] = __float2bfloat16(a.y);
    t[2] = __float2bfloat16(a.z); t[3] = __float2bfloat16(a.w);
    t[4] = __float2bfloat16(b.x); t[5] = __float2bfloat16(b.y);
    t[6] = __float2bfloat16(b.z); t[7] = __float2bfloat16(b.w);
    *(bf16x8*)(&y[(size_t)idx * 8]) = *(bf16x8*)t;
    return;
  }

  int gid = (blockIdx.x - CAST_BLOCKS) * 256 + threadIdx.x;
  int o = gid >> 9;                          // output row (FIN/8 = 512)
  int fs = (gid & 511) << 3;                 // fin start, multiple of 8
  int h = o >> 10;                           // head
  int r = o & (ROWS_PER_HEAD - 1);

  float kk[3][3];
#pragma unroll
  for (int i = 0; i < 3; i++)
#pragma unroll
    for (int j = 0; j < 3; j++) kk[i][j] = cw[h * 9 + i * 3 + j];
  float sig = 1.0f / (1.0f + __expf(-sk[h]));

  float acc[8];
#pragma unroll
  for (int j = 0; j < 8; j++) acc[j] = cb[h];

#pragma unroll
  for (int dr = -1; dr <= 1; dr++) {
    int rr = r + dr;
    if (rr < 0 || rr >= ROWS_PER_HEAD) continue;
    const float* rp = W + ((size_t)(h * ROWS_PER_HEAD + rr)) * FIN + fs;
    float a[10];
    float4 v0 = *(const float4*)rp;
    float4 v1 = *(const float4*)(rp + 4);
    a[1] = v0.x; a[2] = v0.y; a[3] = v0.z; a[4] = v0.w;
    a[5] = v1.x; a[6] = v1.y; a[7] = v1.z; a[8] = v1.w;
    a[0] = (fs > 0) ? rp[-1] : 0.0f;
    a[9] = (fs + 8 < FIN) ? rp[8] : 0.0f;
#pragma unroll
    for (int j = 0; j < 8; j++)
      acc[j] += kk[dr + 1][0] * a[j] + kk[dr + 1][1] * a[j + 1] +
                kk[dr + 1][2] * a[j + 2];
    if (dr == 0) {
#pragma unroll
      for (int j = 0; j < 8; j++) acc[j] += sig * a[j + 1];
    }
  }
  __hip_bfloat16 t[8];
#pragma unroll
  for (int j = 0; j < 8; j++) t[j] = __float2bfloat16(acc[j]);
  *(bf16x8*)(&Wt[(size_t)o * FIN + fs]) = *(bf16x8*)t;
}

// ---------------------------------------------------------------------------
// Kernel 2: C[m][n] = sum_k A[m][k] * B[n][k]  (NT GEMM, bf16 in, FP32 out)
// R7: BK=64 (barriers halve vs BK=32; 32 KB LDS keeps 4 blocks/CU residency).
// LDS rows are 128 B (64 bf16) = 8 x 16B chunks, bank-aligned. Slot s of row
// r holds global chunk g = s ^ (r&7). Fragment (fr,quad,kk) reads slot
// (kk*4+quad)^(fr&7): every 8-lane phase covers all 32 banks exactly once.
// ---------------------------------------------------------------------------
__device__ static inline void gload_lds16(const void* g, void* l) {
  __builtin_amdgcn_global_load_lds(
      (const __attribute__((address_space(1))) void*)g,
      (__attribute__((address_space(3))) void*)l, 16, 0, 0);
}

__global__ __launch_bounds__(256, 3) void gemm_nt(
    const __hip_bfloat16* __restrict__ A,  // [M][K]
    const __hip_bfloat16* __restrict__ B,  // [N][K]  (= W_i, row-major)
    float* __restrict__ C,                 // [M][N] fp32
    int M, int N, int K) {
  __shared__ __hip_bfloat16 As[128 * 64];  // 16 KB
  __shared__ __hip_bfloat16 Bs[128 * 64];  // 16 KB

  const int tid = threadIdx.x;
  const int lane = tid & 63;
  const int wave = tid >> 6;  // 0..3
  const int tile_m = blockIdx.y * 128;
  const int tile_n = blockIdx.x * 128;

  const int fr = lane & 15;    // fragment row (m for A, n for B^T)
  const int quad = lane >> 4;  // k-chunk selector (k = kk*32 + quad*8 + j)
  const int wm = (wave & 1) * 64;
  const int wn = (wave >> 1) * 64;
  const int selA = fr & 7;     // swizzle selector (= row&7 for fragment rows)

  floatx4 acc[4][4];
#pragma unroll
  for (int i = 0; i < 4; i++)
#pragma unroll
    for (int j = 0; j < 4; j++) acc[i][j] = (floatx4){0.f, 0.f, 0.f, 0.f};

  for (int k0 = 0; k0 < K; k0 += 64) {
    // Stage 128x64 bf16 = 1024 16B-chunks each for A and B; 4+4 per thread.
    // Chunk position p: row = p>>3, slot = p&7 holds global chunk
    // g = (p&7)^(row&7). Lanes 0..7 of a group cover one full 128 B row
    // (lane-permuted within the line) -> coalesced fetch.
#pragma unroll
    for (int t = 0; t < 4; t++) {
      int base = (t * 4 + wave) * 64;  // wave-uniform chunk base
      int p = base + lane;             // LDS chunk position
      int row = p >> 3;
      int g = (p & 7) ^ (row & 7);     // permuted global chunk
      gload_lds16(&A[(size_t)(tile_m + row) * K + k0 + g * 8],
                  &As[base * 8]);
      gload_lds16(&B[(size_t)(tile_n + row) * K + k0 + g * 8],
                  &Bs[base * 8]);
    }
    __syncthreads();

#pragma unroll
    for (int kk = 0; kk < 2; kk++) {
      const int sA = ((kk * 4 + quad) ^ selA) * 8;  // swizzled byte/2 offset
      bf16x8 a_frag[4], b_frag[4];
#pragma unroll
      for (int i = 0; i < 4; i++) {
        a_frag[i] = *(const bf16x8*)(&As[(wm + i * 16 + fr) * 64 + sA]);
        b_frag[i] = *(const bf16x8*)(&Bs[(wn + i * 16 + fr) * 64 + sA]);
      }
#pragma unroll
      for (int i = 0; i < 4; i++)
#pragma unroll
        for (int j = 0; j < 4; j++)
          acc[i][j] = __builtin_amdgcn_mfma_f32_16x16x32_bf16(
              a_frag[i], b_frag[j], acc[i][j], 0, 0, 0);
    }
    __syncthreads();
  }

  // Epilogue: C/D layout col = lane&15, row = quad*4 + reg. FP32 stores.
#pragma unroll
  for (int i = 0; i < 4; i++) {
    int m_base = tile_m + wm + i * 16 + quad * 4;
#pragma unroll
    for (int j = 0; j < 4; j++) {
      int n = tile_n + wn + j * 16 + fr;
#pragma unroll
      for (int r = 0; r < 4; r++) {
        C[(size_t)(m_base + r) * N + n] = acc[i][j][r];
      }
    }
  }
}

// ---------------------------------------------------------------------------
extern "C" void kernel_launch(void* const* d_in, const int* in_sizes, int n_in,
                              void* d_out, int out_size, void* d_ws,
                              size_t ws_size, hipStream_t stream) {
  const float* inp = (const float*)d_in[0];     // [2,2048,4096] fp32
  const float* W = (const float*)d_in[1];       // [4096,4096] fp32
  const float* conv_w = (const float*)d_in[2];  // [4,1,3,3] fp32
  const float* conv_b = (const float*)d_in[3];  // [4] fp32
  const float* sk_wt = (const float*)d_in[4];   // [4,1,1] fp32
  float* out = (float*)d_out;                   // [2,2048,4096] fp32

  __hip_bfloat16* Wt = (__hip_bfloat16*)d_ws;   // 32 MB
  __hip_bfloat16* Ab =
      (__hip_bfloat16*)((char*)d_ws + (size_t)(32u << 20));  // next 32 MB

  // 1) merged prep: cast activations + transform weight, one launch
  prep<<<CAST_BLOCKS + TRANS_BLOCKS, 256, 0, stream>>>(inp, Ab, W, conv_w,
                                                       conv_b, sk_wt, Wt);
  // 2) out[m][n] = sum_k Ab[m][k] * Wt[n][k]
  dim3 grid(FOUT / 128, M_DIM / 128);
  gemm_nt<<<grid, 256, 0, stream>>>(Ab, Wt, out, M_DIM, FOUT, FIN);
}